// Round 2
// baseline (256.904 us; speedup 1.0000x reference)
//
#include <hip/hip_runtime.h>
#include <math.h>

#define IMG_W 2048
#define IMG_H 2048
#define BATCH 8
#define MAX_PEAKS ((BATCH * IMG_H * IMG_W) / 8)   // 4194304
#define NWORDS (BATCH * IMG_H * IMG_W / 32)       // 1048576
#define ROWSW 32                                  // rows per wave
#define NFILL 2048                                // tail-fill blocks

// ---------------------------------------------------------------------------
// K1: register-ring NMS mask. Hot loop is now PURE load + VALU:
//  - no per-row global store, no per-row ds_bpermute, no divergent branch.
//  - each lane accumulates its 4-col nibble per row into a packed 32-bit
//    register (8 rows x 4 bits); the shuffle-merge + words[] store happens
//    once per 8-row group in a batched epilogue (MERGE8).
// This keeps the vmcnt stream clean (loads only) so the distance-3 prefetch
// ring actually pipelines, and removes ~7 DS ops + 1 divergent store per row
// from the critical path.
// mask bit = (s > 0) && (s >= 5x5 window max); -inf outside the image.
// ---------------------------------------------------------------------------

#define NMS_COMPUTE(uu)                                                       \
  {                                                                           \
    const float4 w0 = ring[(uu) & 7];                                         \
    const float4 w1 = ring[((uu) + 1) & 7];                                   \
    const float4 mid = ring[((uu) + 2) & 7];                                  \
    const float4 w3 = ring[((uu) + 3) & 7];                                   \
    const float4 w4 = ring[((uu) + 4) & 7];                                   \
    float vmx = fmaxf(fmaxf(fmaxf(w0.x, w1.x), fmaxf(mid.x, w3.x)), w4.x);    \
    float vmy = fmaxf(fmaxf(fmaxf(w0.y, w1.y), fmaxf(mid.y, w3.y)), w4.y);    \
    float vmz = fmaxf(fmaxf(fmaxf(w0.z, w1.z), fmaxf(mid.z, w3.z)), w4.z);    \
    float vmw = fmaxf(fmaxf(fmaxf(w0.w, w1.w), fmaxf(mid.w, w3.w)), w4.w);    \
    const float2 e0 = ringE[(uu) & 7];                                        \
    const float2 e1 = ringE[((uu) + 1) & 7];                                  \
    const float2 e2 = ringE[((uu) + 2) & 7];                                  \
    const float2 e3 = ringE[((uu) + 3) & 7];                                  \
    const float2 e4 = ringE[((uu) + 4) & 7];                                  \
    float vex = fmaxf(fmaxf(fmaxf(e0.x, e1.x), fmaxf(e2.x, e3.x)), e4.x);     \
    float vey = fmaxf(fmaxf(fmaxf(e0.y, e1.y), fmaxf(e2.y, e3.y)), e4.y);     \
    float Av = __shfl_up(vmz, 1);                                             \
    float Bv = __shfl_up(vmw, 1);                                             \
    float Cv = __shfl_down(vmx, 1);                                           \
    float Dv = __shfl_down(vmy, 1);                                           \
    if (isL) { Av = vex; Bv = vey; }                                          \
    if (isR) { Cv = vex; Dv = vey; }                                          \
    float t12 = fmaxf(vmy, vmz);                                              \
    float m02 = fmaxf(vmx, t12);                                              \
    float m03 = fmaxf(m02, vmw);                                              \
    float m13 = fmaxf(t12, vmw);                                              \
    float h0 = fmaxf(fmaxf(Av, Bv), m02);                                     \
    float h1 = fmaxf(Bv, m03);                                                \
    float h2 = fmaxf(m03, Cv);                                                \
    float h3 = fmaxf(m13, fmaxf(Cv, Dv));                                     \
    unsigned nib = 0;                                                         \
    nib |= (mid.x > 0.0f && mid.x >= h0) ? 1u : 0u;                           \
    nib |= (mid.y > 0.0f && mid.y >= h1) ? 2u : 0u;                           \
    nib |= (mid.z > 0.0f && mid.z >= h2) ? 4u : 0u;                           \
    nib |= (mid.w > 0.0f && mid.w >= h3) ? 8u : 0u;                           \
    bacc |= nib << (4 * (uu));                                                \
  }

// batched merge + store for one 8-row group (rows i8v*8 .. i8v*8+7)
#define MERGE8(i8v, bb)                                                       \
  {                                                                           \
    _Pragma("unroll")                                                         \
    for (int q = 0; q < 8; ++q) {                                             \
      unsigned wd = (((bb) >> (q * 4)) & 0xFu) << shamt;                      \
      wd |= __shfl_xor(wd, 1);                                                \
      wd |= __shfl_xor(wd, 2);                                                \
      wd |= __shfl_xor(wd, 4);                                                \
      if ((lane & 7) == 0) {                                                  \
        words[wRow + (size_t)((i8v) * 8 + q) * (IMG_W / 32)] = wd;            \
        cnt += __popc(wd);                                                    \
      }                                                                       \
    }                                                                         \
  }

// fast-path prefetch: unclamped pointer stepping, distance 3 -> slot (uu+7)&7
#define PF_FAST(uu)                                                           \
  {                                                                           \
    ring[((uu) + 7) & 7] = *(const float4*)p;                                 \
    const float2 _e = *(const float2*)pe;                                     \
    float2 _ne;                                                               \
    _ne.x = evalid ? _e.x : NEG;                                              \
    _ne.y = evalid ? _e.y : NEG;                                              \
    ringE[((uu) + 7) & 7] = _ne;                                              \
    p += IMG_W;                                                               \
    pe += IMG_W;                                                              \
  }

// slow-path prefetch: row clamp + validity selects, same slot math
#define PF_SLOW(uu, gr)                                                       \
  {                                                                           \
    const int _rc = (gr) < 0 ? 0 : ((gr) > IMG_H - 1 ? IMG_H - 1 : (gr));     \
    const size_t _off = (size_t)_rc * IMG_W;                                  \
    const float4 _v = *(const float4*)(colp + _off);                          \
    const float2 _e = *(const float2*)(ecolp + _off);                         \
    const bool _rv = ((unsigned)(gr) < (unsigned)IMG_H);                      \
    const bool _ok = _rv && evalid;                                           \
    float4 _nv;                                                               \
    float2 _ne;                                                               \
    _nv.x = _rv ? _v.x : NEG;                                                 \
    _nv.y = _rv ? _v.y : NEG;                                                 \
    _nv.z = _rv ? _v.z : NEG;                                                 \
    _nv.w = _rv ? _v.w : NEG;                                                 \
    _ne.x = _ok ? _e.x : NEG;                                                 \
    _ne.y = _ok ? _e.y : NEG;                                                 \
    ring[((uu) + 7) & 7] = _nv;                                               \
    ringE[((uu) + 7) & 7] = _ne;                                              \
  }

#define FLUSH(k)                                                              \
  {                                                                           \
    unsigned s = cnt;                                                         \
    s += __shfl_xor(s, 1);                                                    \
    s += __shfl_xor(s, 2);                                                    \
    s += __shfl_xor(s, 4);                                                    \
    s += __shfl_xor(s, 8);                                                    \
    s += __shfl_xor(s, 16);                                                   \
    s += __shfl_xor(s, 32);                                                   \
    if (lane == 0) bsum2[(cb0 + (k)) * 8 + strip] = s;                        \
    cnt = 0;                                                                  \
  }

__global__ __launch_bounds__(256, 4) void nms_mask(const float* __restrict__ scores,
                                                   unsigned* __restrict__ words,
                                                   unsigned* __restrict__ bsum2) {
    const int t = threadIdx.x;
    const int lane = t & 63;
    const int wv = t >> 6;
    const int b = blockIdx.x;         // 0..1023
    const int img = b >> 7;           // 8 images x 128 blocks
    const int rem = b & 127;
    const int strip = rem >> 4;       // 8 column strips of 256
    const int chunk = rem & 15;       // 16 row chunks of 128
    const int r0 = chunk * 128 + wv * ROWSW;
    const int c0 = strip * 256;
    const int cl = c0 + lane * 4;
    const size_t imgBase = (size_t)img * ((size_t)IMG_H * IMG_W);
    const float NEG = -INFINITY;

    const float* colp = scores + imgBase + cl;
    const bool leftHalf = (lane < 32);
    const bool isL = (lane == 0), isR = (lane == 63);
    // float2 edge halo: left half needs cols (c0-2,c0-1); right half (c0+256,c0+257)
    const int ecol2 = leftHalf ? (c0 - 2) : (c0 + 256);
    const bool evalid = ((unsigned)ecol2 < (unsigned)IMG_W);
    const int ecol2C = evalid ? ecol2 : c0;     // clamped valid address
    const float* ecolp = scores + imgBase + ecol2C;

    float4 ring[8];
    float2 ringE[8];

    unsigned cnt = 0;
    const int shamt = (lane & 7) * 4;
    const size_t wRow = (size_t)(img * IMG_H + r0) * (IMG_W / 32) + strip * 8 + (lane >> 3);
    const int cb0 = (img * IMG_H + r0) >> 4;   // compact-block (16-row) index

    // interior: warm-up rows r0-2..r0+4 and steady rows up to r0+33 all valid
    const bool rowsInterior = (r0 >= 2) && (r0 + 33 <= IMG_H - 1);

    if (rowsInterior) {
        const float* p = colp + (size_t)(r0 - 2) * IMG_W;
        const float* pe = ecolp + (size_t)(r0 - 2) * IMG_W;
        // warm-up: rows r0-2..r0+4 -> slots 0..6
#pragma unroll
        for (int m = 0; m < 7; ++m) {
            ring[m] = *(const float4*)p;
            const float2 _e = *(const float2*)pe;
            ringE[m].x = evalid ? _e.x : NEG;
            ringE[m].y = evalid ? _e.y : NEG;
            p += IMG_W;
            pe += IMG_W;
        }
        // p now at row r0+5: the U=0 prefetch (consumed at U=3)
#pragma unroll 1
        for (int i8 = 0; i8 < 2; ++i8) {   // groups 0,1 (rows 0..15)
            unsigned bacc = 0;
#pragma unroll
            for (int uu = 0; uu < 8; ++uu) {
                PF_FAST(uu);
                NMS_COMPUTE(uu);
            }
            MERGE8(i8, bacc);
        }
        FLUSH(0);
        {   // group 2 (rows 16..23)
            unsigned bacc = 0;
#pragma unroll
            for (int uu = 0; uu < 8; ++uu) {
                PF_FAST(uu);
                NMS_COMPUTE(uu);
            }
            MERGE8(2, bacc);
        }
        {   // group 3 (rows 24..31); last useful load is row r0+33
            unsigned bacc = 0;
#pragma unroll
            for (int uu = 0; uu < 5; ++uu) {
                PF_FAST(uu);
                NMS_COMPUTE(uu);
            }
#pragma unroll
            for (int uu = 5; uu < 8; ++uu) {
                NMS_COMPUTE(uu);
            }
            MERGE8(3, bacc);
        }
        FLUSH(1);
    } else {
        // warm-up: rows r0-2..r0+4 -> slots 0..6 (clamped + -inf selects)
#pragma unroll
        for (int m = 0; m < 7; ++m) {
            PF_SLOW(m - 7, r0 - 2 + m);
        }
#pragma unroll 1
        for (int i8 = 0; i8 < 4; ++i8) {
            unsigned bacc = 0;
#pragma unroll
            for (int uu = 0; uu < 8; ++uu) {
                const int U = i8 * 8 + uu;
                PF_SLOW(uu, r0 + U + 5);   // rows past r0+33 are clamped dups, unused
                NMS_COMPUTE(uu);
            }
            MERGE8(i8, bacc);
            if (i8 & 1) FLUSH(i8 >> 1);
        }
    }
}

// ---------------------------------------------------------------------------
// K2 is GONE: each compact/fill block self-scans bsum2 (32 KB, L2-resident
// after first touch) to get its exclusive base / the grand total. This kills
// the single-block scan kernel's launch + dependency bubble; aggregate extra
// L2 read traffic is ~100 MB @ 34 TB/s ≈ 3 µs, overlapped.
// ---------------------------------------------------------------------------
__global__ __launch_bounds__(256) void nms_compact(const unsigned* __restrict__ words,
                                                   const unsigned* __restrict__ bsum2,
                                                   int* __restrict__ out) {
    const int t = threadIdx.x;
    const int b = blockIdx.x;
    const int lane = t & 63, wid = t >> 6;
    __shared__ unsigned sred[4];
    __shared__ unsigned wq[4];

    // ---- self-scan: sum bsum2[0 .. lim) (uint4-vectorized; lim % 8 == 0) ----
    const int limq = ((b < 1024) ? (b * 8) : 8192) >> 2;   // uint4 count
    unsigned acc = 0;
    const uint4* p4 = (const uint4*)bsum2;
    for (int i = t; i < limq; i += 256) {
        uint4 a = p4[i];
        acc += a.x + a.y + a.z + a.w;
    }
    acc += __shfl_xor(acc, 1);
    acc += __shfl_xor(acc, 2);
    acc += __shfl_xor(acc, 4);
    acc += __shfl_xor(acc, 8);
    acc += __shfl_xor(acc, 16);
    acc += __shfl_xor(acc, 32);
    if (lane == 0) sred[wid] = acc;
    __syncthreads();
    const unsigned basev = sred[0] + sred[1] + sred[2] + sred[3];

    if (b < 1024) {
        // ---- ordered compaction of 1024 words (16 rows, full width) ----
        uint4 q = ((const uint4*)(words + b * 1024))[t];
        unsigned wv[4] = {q.x, q.y, q.z, q.w};
        unsigned tsum = __popc(wv[0]) + __popc(wv[1]) + __popc(wv[2]) + __popc(wv[3]);
        unsigned sc = tsum;
#pragma unroll
        for (int d = 1; d < 64; d <<= 1) {
            unsigned o = __shfl_up(sc, d);
            if (lane >= d) sc += o;
        }
        if (lane == 63) wq[wid] = sc;
        __syncthreads();
        unsigned wpre = 0;
#pragma unroll
        for (int k = 0; k < 4; ++k) wpre += (k < wid) ? wq[k] : 0u;
        unsigned off = basev + wpre + sc - tsum;

        const unsigned gword0 = (unsigned)b * 1024u + (unsigned)t * 4u;
#pragma unroll
        for (int wi = 0; wi < 4; ++wi) {
            unsigned m = wv[wi];
            unsigned pbase = (gword0 + wi) << 5;
            while (m) {
                int bit = __builtin_ctz(m);
                m &= m - 1;
                unsigned ppix = pbase + (unsigned)bit;
                int hh = (int)((ppix >> 11) & 2047u);
                int ww = (int)(ppix & 2047u);
                if (off < (unsigned)MAX_PEAKS) {
                    out[off] = hh;
                    out[MAX_PEAKS + off] = ww;
                }
                ++off;
            }
        }
    } else {
        // ---- -1 tail fill, int4-vectorized on the aligned body ----
        unsigned total = basev;
        if (total > (unsigned)MAX_PEAKS) total = MAX_PEAKS;
        unsigned tail = (unsigned)MAX_PEAKS - total;
        unsigned fb = (unsigned)(b - 1024);
        unsigned per = (tail + NFILL - 1) / NFILL;
        unsigned s = total + fb * per;
        unsigned e = s + per;
        if (s > (unsigned)MAX_PEAKS) s = MAX_PEAKS;
        if (e > (unsigned)MAX_PEAKS) e = MAX_PEAKS;
        unsigned a = (s + 3u) & ~3u;
        if (a > e) a = e;
        unsigned e4 = e & ~3u;
        if (e4 < a) e4 = a;
        // head scalars [s, a)  (<=3 elems)
        if ((unsigned)t < a - s) {
            out[s + t] = -1;
            out[MAX_PEAKS + s + t] = -1;
        }
        // aligned body [a, e4) as int4 (MAX_PEAKS % 4 == 0 -> both planes aligned)
        const int4 m4 = make_int4(-1, -1, -1, -1);
        for (unsigned k = a / 4 + t; k < e4 / 4; k += 256) {
            ((int4*)out)[k] = m4;
            ((int4*)(out + MAX_PEAKS))[k] = m4;
        }
        // tail scalars [e4, e)  (<=3 elems)
        if ((unsigned)t < e - e4) {
            out[e4 + t] = -1;
            out[MAX_PEAKS + e4 + t] = -1;
        }
    }
}

extern "C" void kernel_launch(void* const* d_in, const int* in_sizes, int n_in,
                              void* d_out, int out_size, void* d_ws, size_t ws_size,
                              hipStream_t stream) {
    const float* scores = (const float*)d_in[0];
    int* out = (int*)d_out;
    unsigned* words = (unsigned*)d_ws;            // 1,048,576 words (4 MB)
    unsigned* bsum2 = words + NWORDS;             // 8192 per-(chunk,strip) sums

    nms_mask<<<1024, 256, 0, stream>>>(scores, words, bsum2);
    nms_compact<<<1024 + NFILL, 256, 0, stream>>>(words, bsum2, out);
}

// Round 3
// 216.738 us; speedup vs baseline: 1.1853x; 1.1853x over previous
//
#include <hip/hip_runtime.h>
#include <math.h>

#define IMG_W 2048
#define IMG_H 2048
#define BATCH 8
#define MAX_PEAKS ((BATCH * IMG_H * IMG_W) / 8)   // 4194304
#define NWORDS (BATCH * IMG_H * IMG_W / 32)       // 1048576
#define NFILL 2048                                // tail-fill blocks

// ---------------------------------------------------------------------------
// K1: separable NMS mask. 5x5 max = vertical-5-max of horizontal-5-maxes.
// Wave = 64 lanes x 4 cols (256-col strip) x 16 rows. Grid 2048 blocks
// (8 blocks/CU -> 32 waves/CU possible). Rings are NAMED float4 registers
// (no arrays -> cannot go to scratch):
//   R0..R3  raw row delay line (mid for the compare, 4 deep)
//   H0..H4  horizontal-max ring (5 deep)
//   E0,E1   edge halo float2 ring (2 deep)
// = 40 ring VGPRs; __launch_bounds__(256,6) caps at 80 -> no spill, >=24
// waves/CU. Border rows handled by CLAMPED pointer stepping (max is
// idempotent under row replication == -inf padding semantics); horizontal
// edges via -inf selects on the 8B edge load. XCD swizzle: image i -> XCD i,
// so vertical halo rows re-read by adjacent chunks hit that XCD's L2.
// mask bit = (s > 0) && (s >= 5x5 window max).
// ---------------------------------------------------------------------------

// load current row into raw slot RS + edge slot ES, clamped pointer step
#define LOADR(RS, ES)                                                         \
  {                                                                           \
    RS = *(const float4*)p;                                                   \
    const float2 _e = *(const float2*)pe;                                     \
    ES.x = evalid ? _e.x : NEG;                                               \
    ES.y = evalid ? _e.y : NEG;                                               \
    const size_t stepB =                                                      \
        ((unsigned)(xn - 1) < 2047u) ? (size_t)(IMG_W * 4) : (size_t)0;       \
    p = (const float*)((const char*)p + stepB);                               \
    pe = (const float*)((const char*)pe + stepB);                             \
    ++xn;                                                                     \
  }

// horizontal 5-max of raw row RS (+edge ES) -> HS
#define HMR(RS, ES, HS)                                                       \
  {                                                                           \
    float Av = __shfl_up(RS.z, 1);                                            \
    float Bv = __shfl_up(RS.w, 1);                                            \
    float Cv = __shfl_down(RS.x, 1);                                          \
    float Dv = __shfl_down(RS.y, 1);                                          \
    if (isL) { Av = ES.x; Bv = ES.y; }                                        \
    if (isR) { Cv = ES.x; Dv = ES.y; }                                        \
    const float t12 = fmaxf(RS.y, RS.z);                                      \
    const float m02 = fmaxf(RS.x, t12);                                       \
    const float m03 = fmaxf(m02, RS.w);                                       \
    const float m13 = fmaxf(t12, RS.w);                                       \
    HS.x = fmaxf(fmaxf(Av, Bv), m02);                                         \
    HS.y = fmaxf(Bv, m03);                                                    \
    HS.z = fmaxf(m03, Cv);                                                    \
    HS.w = fmaxf(m13, fmaxf(Cv, Dv));                                         \
  }

// output one row: vertical max over all 5 hm slots, compare vs mid raw MR
#define OUTR(MR)                                                              \
  {                                                                           \
    const float mx = fmaxf(fmaxf(fmaxf(H0.x, H1.x), fmaxf(H2.x, H3.x)), H4.x);\
    const float my = fmaxf(fmaxf(fmaxf(H0.y, H1.y), fmaxf(H2.y, H3.y)), H4.y);\
    const float mz = fmaxf(fmaxf(fmaxf(H0.z, H1.z), fmaxf(H2.z, H3.z)), H4.z);\
    const float mw = fmaxf(fmaxf(fmaxf(H0.w, H1.w), fmaxf(H2.w, H3.w)), H4.w);\
    unsigned nib = 0;                                                         \
    nib |= (MR.x > 0.0f && MR.x >= mx) ? 1u : 0u;                             \
    nib |= (MR.y > 0.0f && MR.y >= my) ? 2u : 0u;                             \
    nib |= (MR.z > 0.0f && MR.z >= mz) ? 4u : 0u;                             \
    nib |= (MR.w > 0.0f && MR.w >= mw) ? 8u : 0u;                             \
    unsigned wd = nib << shamt;                                               \
    wd |= __shfl_xor(wd, 1);                                                  \
    wd |= __shfl_xor(wd, 2);                                                  \
    wd |= __shfl_xor(wd, 4);                                                  \
    if ((lane & 7) == 0) {                                                    \
      words[wIdx] = wd;                                                       \
      cnt += __popc(wd);                                                      \
    }                                                                         \
    wIdx += IMG_W / 32;                                                       \
  }

__global__ __launch_bounds__(256, 6) void nms_mask(const float* __restrict__ scores,
                                                   unsigned* __restrict__ words,
                                                   unsigned* __restrict__ bsum2) {
    const int t = threadIdx.x;
    const int lane = t & 63;
    const int wv = t >> 6;
    // XCD swizzle: hardware assigns block b -> XCD (b & 7). Logical id L puts
    // all 256 blocks of image (b&7) on one XCD, consecutive b/8 = consecutive
    // row chunks of a strip -> vertical halo rows L2-hit within the XCD.
    const int b = blockIdx.x;                 // 0..2047
    const int L = (b >> 3) + (b & 7) * 256;
    const int img = L >> 8;                   // 8 images
    const int rem = L & 255;
    const int strip = rem >> 5;               // 8 strips of 256 cols
    const int chunk = rem & 31;               // 32 chunks of 64 rows
    const int r0 = chunk * 64 + wv * 16;      // 16 rows per wave
    const int c0 = strip * 256;
    const int cl = c0 + lane * 4;
    const size_t imgBase = (size_t)img * ((size_t)IMG_H * IMG_W);
    const float NEG = -INFINITY;

    const bool leftHalf = (lane < 32);
    const bool isL = (lane == 0), isR = (lane == 63);
    // edge halo float2: left half lanes carry cols (c0-2,c0-1); right half
    // (c0+256,c0+257). Only lanes 0/63 consume.
    const int ecol2 = leftHalf ? (c0 - 2) : (c0 + 256);
    const bool evalid = ((unsigned)ecol2 < (unsigned)IMG_W);
    const int ecol2C = evalid ? ecol2 : c0;

    const int rstart = (r0 - 2) < 0 ? 0 : (r0 - 2);   // clamped first row
    const float* p = scores + imgBase + (size_t)rstart * IMG_W + cl;
    const float* pe = scores + imgBase + (size_t)rstart * IMG_W + ecol2C;
    int xn = r0 - 1;   // row after the one about to be loaded

    float4 R0, R1, R2, R3;
    float4 H0, H1, H2, H3, H4;
    float2 E0, E1;

    unsigned cnt = 0;
    const int shamt = (lane & 7) * 4;
    size_t wIdx = (size_t)(img * IMG_H + r0) * (IMG_W / 32) + strip * 8 + (lane >> 3);
    const int cb0 = (img * IMG_H + r0) >> 4;   // this wave's 16-row block index

    // schedule: iter u loads row r0-1+u into R[(u+1)&3]/E[(u+1)&1], computes
    // hm of row r0-2+u from R[u&3]/E[u&1] into H[u%5], and for u>=4 outputs
    // row r0-4+u with mid = R[(u+2)&3]. Distance-1 prefetch; all slots named.
    LOADR(R0, E0);                              // row r0-2
    LOADR(R1, E1); HMR(R0, E0, H0);             // u=0
    LOADR(R2, E0); HMR(R1, E1, H1);             // u=1
    LOADR(R3, E1); HMR(R2, E0, H2);             // u=2
    LOADR(R0, E0); HMR(R3, E1, H3);             // u=3
    LOADR(R1, E1); HMR(R0, E0, H4); OUTR(R2);   // u=4  -> row r0
    LOADR(R2, E0); HMR(R1, E1, H0); OUTR(R3);   // u=5
    LOADR(R3, E1); HMR(R2, E0, H1); OUTR(R0);   // u=6
    LOADR(R0, E0); HMR(R3, E1, H2); OUTR(R1);   // u=7
    LOADR(R1, E1); HMR(R0, E0, H3); OUTR(R2);   // u=8
    LOADR(R2, E0); HMR(R1, E1, H4); OUTR(R3);   // u=9
    LOADR(R3, E1); HMR(R2, E0, H0); OUTR(R0);   // u=10
    LOADR(R0, E0); HMR(R3, E1, H1); OUTR(R1);   // u=11
    LOADR(R1, E1); HMR(R0, E0, H2); OUTR(R2);   // u=12
    LOADR(R2, E0); HMR(R1, E1, H3); OUTR(R3);   // u=13
    LOADR(R3, E1); HMR(R2, E0, H4); OUTR(R0);   // u=14
    LOADR(R0, E0); HMR(R3, E1, H0); OUTR(R1);   // u=15
    LOADR(R1, E1); HMR(R0, E0, H1); OUTR(R2);   // u=16
    LOADR(R2, E0); HMR(R1, E1, H2); OUTR(R3);   // u=17
    LOADR(R3, E1); HMR(R2, E0, H3); OUTR(R0);   // u=18
                   HMR(R3, E1, H4); OUTR(R1);   // u=19 -> row r0+15

    // per-wave peak count -> unique bsum2 slot (one wave == one 16-row block)
    unsigned s = cnt;
    s += __shfl_xor(s, 1);
    s += __shfl_xor(s, 2);
    s += __shfl_xor(s, 4);
    s += __shfl_xor(s, 8);
    s += __shfl_xor(s, 16);
    s += __shfl_xor(s, 32);
    if (lane == 0) bsum2[cb0 * 8 + strip] = s;
}

// ---------------------------------------------------------------------------
// K3: fused self-scan + ordered compaction (blocks 0..1023) and -1 tail fill
// (blocks 1024..). bsum2 (32 KB) is L2-resident; each block sums its prefix.
// ---------------------------------------------------------------------------
__global__ __launch_bounds__(256) void nms_compact(const unsigned* __restrict__ words,
                                                   const unsigned* __restrict__ bsum2,
                                                   int* __restrict__ out) {
    const int t = threadIdx.x;
    const int b = blockIdx.x;
    const int lane = t & 63, wid = t >> 6;
    __shared__ unsigned sred[4];
    __shared__ unsigned wq[4];

    // ---- self-scan: sum bsum2[0 .. lim) (uint4-vectorized; lim % 8 == 0) ----
    const int limq = ((b < 1024) ? (b * 8) : 8192) >> 2;   // uint4 count
    unsigned acc = 0;
    const uint4* p4 = (const uint4*)bsum2;
    for (int i = t; i < limq; i += 256) {
        uint4 a = p4[i];
        acc += a.x + a.y + a.z + a.w;
    }
    acc += __shfl_xor(acc, 1);
    acc += __shfl_xor(acc, 2);
    acc += __shfl_xor(acc, 4);
    acc += __shfl_xor(acc, 8);
    acc += __shfl_xor(acc, 16);
    acc += __shfl_xor(acc, 32);
    if (lane == 0) sred[wid] = acc;
    __syncthreads();
    const unsigned basev = sred[0] + sred[1] + sred[2] + sred[3];

    if (b < 1024) {
        // ---- ordered compaction of 1024 words (16 rows, full width) ----
        uint4 q = ((const uint4*)(words + b * 1024))[t];
        unsigned wv[4] = {q.x, q.y, q.z, q.w};
        unsigned tsum = __popc(wv[0]) + __popc(wv[1]) + __popc(wv[2]) + __popc(wv[3]);
        unsigned sc = tsum;
#pragma unroll
        for (int d = 1; d < 64; d <<= 1) {
            unsigned o = __shfl_up(sc, d);
            if (lane >= d) sc += o;
        }
        if (lane == 63) wq[wid] = sc;
        __syncthreads();
        unsigned wpre = 0;
#pragma unroll
        for (int k = 0; k < 4; ++k) wpre += (k < wid) ? wq[k] : 0u;
        unsigned off = basev + wpre + sc - tsum;

        const unsigned gword0 = (unsigned)b * 1024u + (unsigned)t * 4u;
#pragma unroll
        for (int wi = 0; wi < 4; ++wi) {
            unsigned m = wv[wi];
            unsigned pbase = (gword0 + wi) << 5;
            while (m) {
                int bit = __builtin_ctz(m);
                m &= m - 1;
                unsigned ppix = pbase + (unsigned)bit;
                int hh = (int)((ppix >> 11) & 2047u);
                int ww = (int)(ppix & 2047u);
                if (off < (unsigned)MAX_PEAKS) {
                    out[off] = hh;
                    out[MAX_PEAKS + off] = ww;
                }
                ++off;
            }
        }
    } else {
        // ---- -1 tail fill, int4-vectorized on the aligned body ----
        unsigned total = basev;
        if (total > (unsigned)MAX_PEAKS) total = MAX_PEAKS;
        unsigned tail = (unsigned)MAX_PEAKS - total;
        unsigned fb = (unsigned)(b - 1024);
        unsigned per = (tail + NFILL - 1) / NFILL;
        unsigned s = total + fb * per;
        unsigned e = s + per;
        if (s > (unsigned)MAX_PEAKS) s = MAX_PEAKS;
        if (e > (unsigned)MAX_PEAKS) e = MAX_PEAKS;
        unsigned a = (s + 3u) & ~3u;
        if (a > e) a = e;
        unsigned e4 = e & ~3u;
        if (e4 < a) e4 = a;
        if ((unsigned)t < a - s) {
            out[s + t] = -1;
            out[MAX_PEAKS + s + t] = -1;
        }
        const int4 m4 = make_int4(-1, -1, -1, -1);
        for (unsigned k = a / 4 + t; k < e4 / 4; k += 256) {
            ((int4*)out)[k] = m4;
            ((int4*)(out + MAX_PEAKS))[k] = m4;
        }
        if ((unsigned)t < e - e4) {
            out[e4 + t] = -1;
            out[MAX_PEAKS + e4 + t] = -1;
        }
    }
}

extern "C" void kernel_launch(void* const* d_in, const int* in_sizes, int n_in,
                              void* d_out, int out_size, void* d_ws, size_t ws_size,
                              hipStream_t stream) {
    const float* scores = (const float*)d_in[0];
    int* out = (int*)d_out;
    unsigned* words = (unsigned*)d_ws;            // 1,048,576 words (4 MB)
    unsigned* bsum2 = words + NWORDS;             // 8192 per-(16-row,strip) sums

    nms_mask<<<2048, 256, 0, stream>>>(scores, words, bsum2);
    nms_compact<<<1024 + NFILL, 256, 0, stream>>>(words, bsum2, out);
}

// Round 4
// 216.641 us; speedup vs baseline: 1.1859x; 1.0005x over previous
//
#include <hip/hip_runtime.h>
#include <math.h>

#define IMG_W 2048
#define IMG_H 2048
#define BATCH 8
#define MAX_PEAKS ((BATCH * IMG_H * IMG_W) / 8)   // 4194304
#define NWORDS (BATCH * IMG_H * IMG_W / 32)       // 1048576
#define NFILL 2048                                // tail-fill blocks

// ---------------------------------------------------------------------------
// K1: separable 5x5 NMS, ZERO per-row cross-lane ops.
// Wave = 64 lanes x 4 cols x 16 rows. Each lane loads 3 aligned float4 per
// row: qL@cl-4, qM@cl, qR@cl+4 (neighbor lanes overlap the same cache lines,
// so unique traffic/wave is unchanged) -> horizontal 5-max entirely in-lane,
// no shuffles, no edge side-load. Rows r-2..r+2 vertical max via 5-deep
// named H ring; mid via 3-deep M ring; loads via 4-slot raw ring at
// distance 3 (9 loads in flight/wave).
// Mask nibbles accumulate in bacc (8 rows x 4 bits); once per 8 rows a
// 3-step shfl_xor 8x8 nibble TRANSPOSE gives each lane one output word ->
// 64-lane coalesced store. DS ops per row: 0.4 (was 7).
// Image borders: row replication via clamped pointer step (max-idempotent);
// col edges: clamped address + -inf cndmask on the 2 edge lanes.
// mask bit = (s > 0) && (s >= 5x5 window max).
// ---------------------------------------------------------------------------

#define LOAD3(i)                                                              \
  {                                                                           \
    q##i##L = *(const float4*)pL;                                             \
    q##i##M = *(const float4*)pM;                                             \
    q##i##R = *(const float4*)pR;                                             \
    const size_t stepB =                                                      \
        ((unsigned)(xn - 1) < 2047u) ? (size_t)(IMG_W * 4) : (size_t)0;       \
    pL += stepB;                                                              \
    pM += stepB;                                                              \
    pR += stepB;                                                              \
    ++xn;                                                                     \
  }

#define COMP(i, HS, MS)                                                       \
  {                                                                           \
    const float qlz = fixL ? NEG : q##i##L.z;                                 \
    const float qlw = fixL ? NEG : q##i##L.w;                                 \
    const float qrx = fixR ? NEG : q##i##R.x;                                 \
    const float qry = fixR ? NEG : q##i##R.y;                                 \
    const float4 qm = q##i##M;                                                \
    const float ab = fmaxf(qm.x, qm.y);                                       \
    const float cd = fmaxf(qm.z, qm.w);                                       \
    const float bc = fmaxf(qm.y, qm.z);                                       \
    const float abcd = fmaxf(ab, cd);                                         \
    HS.x = fmaxf(fmaxf(qlz, qlw), fmaxf(ab, qm.z));                           \
    HS.y = fmaxf(qlw, abcd);                                                  \
    HS.z = fmaxf(abcd, qrx);                                                  \
    HS.w = fmaxf(fmaxf(bc, qm.w), fmaxf(qrx, qry));                           \
    MS = qm;                                                                  \
  }

#define OUT(MS, pos)                                                          \
  {                                                                           \
    const float vx = fmaxf(fmaxf(fmaxf(H0.x, H1.x), fmaxf(H2.x, H3.x)), H4.x);\
    const float vy = fmaxf(fmaxf(fmaxf(H0.y, H1.y), fmaxf(H2.y, H3.y)), H4.y);\
    const float vz = fmaxf(fmaxf(fmaxf(H0.z, H1.z), fmaxf(H2.z, H3.z)), H4.z);\
    const float vw = fmaxf(fmaxf(fmaxf(H0.w, H1.w), fmaxf(H2.w, H3.w)), H4.w);\
    unsigned nib = 0;                                                         \
    nib |= (MS.x > 0.0f && MS.x >= vx) ? 1u : 0u;                             \
    nib |= (MS.y > 0.0f && MS.y >= vy) ? 2u : 0u;                             \
    nib |= (MS.z > 0.0f && MS.z >= vz) ? 4u : 0u;                             \
    nib |= (MS.w > 0.0f && MS.w >= vw) ? 8u : 0u;                             \
    bacc |= nib << (4 * (pos));                                               \
  }

// 8x8 nibble transpose across each aligned octet of lanes, then store:
// lane (o*8+l) ends holding the mask word of row (base + l), word-col
// (strip*8 + o). One coalesced 64-lane store per 8 rows.
#define MERGE(g)                                                              \
  {                                                                           \
    unsigned x = bacc, y;                                                     \
    y = __shfl_xor(x, 4);                                                     \
    x = (lane & 4) ? ((y >> 16) | (x & 0xFFFF0000u))                          \
                   : ((x & 0x0000FFFFu) | (y << 16));                         \
    y = __shfl_xor(x, 2);                                                     \
    x = (lane & 2) ? (((y >> 8) & 0x00FF00FFu) | (x & 0xFF00FF00u))           \
                   : ((x & 0x00FF00FFu) | ((y << 8) & 0xFF00FF00u));          \
    y = __shfl_xor(x, 1);                                                     \
    x = (lane & 1) ? (((y >> 4) & 0x0F0F0F0Fu) | (x & 0xF0F0F0F0u))           \
                   : ((x & 0x0F0F0F0Fu) | ((y << 4) & 0xF0F0F0F0u));          \
    words[wIdx0 + (g) * 512u] = x;                                            \
    cnt += __popc(x);                                                         \
    bacc = 0;                                                                 \
  }

__global__ __launch_bounds__(256, 4) void nms_mask(const float* __restrict__ scores,
                                                   unsigned* __restrict__ words,
                                                   unsigned* __restrict__ bsum2) {
    const int t = threadIdx.x;
    const int lane = t & 63;
    const int wv = t >> 6;
    // XCD swizzle: block b -> XCD (b&7); logical id groups one image per XCD
    // so vertical halo rows re-read by adjacent chunks L2-hit.
    const int b = blockIdx.x;                 // 0..2047
    const int L = (b >> 3) + (b & 7) * 256;
    const int img = L >> 8;
    const int rem = L & 255;
    const int strip = rem >> 5;               // 8 strips of 256 cols
    const int chunk = rem & 31;               // 32 chunks of 64 rows
    const int r0 = chunk * 64 + wv * 16;      // 16 rows per wave
    const int c0 = strip * 256;
    const int cl = c0 + lane * 4;
    const size_t imgBase = (size_t)img * ((size_t)IMG_H * IMG_W);
    const float NEG = -INFINITY;

    const bool fixL = (lane == 0) && (strip == 0);
    const bool fixR = (lane == 63) && (strip == 7);

    const int rstart = (r0 - 2) < 0 ? 0 : (r0 - 2);
    const char* rowp = (const char*)(scores + imgBase + (size_t)rstart * IMG_W);
    // clamped addresses for the 2 image-edge lanes (values replaced by -inf)
    const char* pL = rowp + 4 * (cl - 4) + (fixL ? 16 : 0);
    const char* pM = rowp + 4 * cl;
    const char* pR = rowp + 4 * (cl + 4) - (fixR ? 16 : 0);
    int xn = r0 - 1;   // virtual-row clamping counter (replicate rows 0/2047)

    float4 q0L, q0M, q0R, q1L, q1M, q1R, q2L, q2M, q2R, q3L, q3M, q3R;
    float4 H0, H1, H2, H3, H4;
    float4 m0, m1, m2;

    unsigned cnt = 0, bacc = 0;
    const unsigned wIdx0 =
        (unsigned)(img * IMG_H + r0 + (lane & 7)) * 64u + strip * 8u + (lane >> 3);
    const int cb0 = (img * IMG_H + r0) >> 4;

    // warmup: rows r0-2, r0-1, r0 -> slots 0,1,2
    LOAD3(0); LOAD3(1); LOAD3(2);
    // steady: iter u loads row r0+1+u into slot (u+3)&3 (distance 3),
    // computes H/mid of row r0-2+u from slot u&3, outputs row r0-4+u (u>=4).
    LOAD3(3); COMP(0, H0, m0);
    LOAD3(0); COMP(1, H1, m1);
    LOAD3(1); COMP(2, H2, m2);
    LOAD3(2); COMP(3, H3, m0);
    LOAD3(3); COMP(0, H4, m1); OUT(m2, 0);
    LOAD3(0); COMP(1, H0, m2); OUT(m0, 1);
    LOAD3(1); COMP(2, H1, m0); OUT(m1, 2);
    LOAD3(2); COMP(3, H2, m1); OUT(m2, 3);
    LOAD3(3); COMP(0, H3, m2); OUT(m0, 4);
    LOAD3(0); COMP(1, H4, m0); OUT(m1, 5);
    LOAD3(1); COMP(2, H0, m1); OUT(m2, 6);
    LOAD3(2); COMP(3, H1, m2); OUT(m0, 7); MERGE(0);
    LOAD3(3); COMP(0, H2, m0); OUT(m1, 0);
    LOAD3(0); COMP(1, H3, m1); OUT(m2, 1);
    LOAD3(1); COMP(2, H4, m2); OUT(m0, 2);
    LOAD3(2); COMP(3, H0, m0); OUT(m1, 3);
    LOAD3(3); COMP(0, H1, m1); OUT(m2, 4);
              COMP(1, H2, m2); OUT(m0, 5);
              COMP(2, H3, m0); OUT(m1, 6);
              COMP(3, H4, m1); OUT(m2, 7); MERGE(1);

    // per-wave peak count -> unique bsum2 slot (one wave == one 16-row block)
    unsigned s = cnt;
    s += __shfl_xor(s, 1);
    s += __shfl_xor(s, 2);
    s += __shfl_xor(s, 4);
    s += __shfl_xor(s, 8);
    s += __shfl_xor(s, 16);
    s += __shfl_xor(s, 32);
    if (lane == 0) bsum2[cb0 * 8 + strip] = s;
}

// ---------------------------------------------------------------------------
// K2: scan. Reduce 8 strip-sums per 16-row chunk (8192 slots -> 1024 cbs),
// exclusive scan, base[1024] = total. One 256-thread block.
// ---------------------------------------------------------------------------
__global__ __launch_bounds__(256) void nms_scan(const unsigned* __restrict__ bsum2,
                                                unsigned* __restrict__ base) {
    __shared__ unsigned wtot[4];
    const int t = threadIdx.x;
    const int lane = t & 63, wid = t >> 6;
    const uint4* p = (const uint4*)(bsum2 + t * 32);   // 4 cbs x 8 slots
    unsigned c[4];
#pragma unroll
    for (int i = 0; i < 4; ++i) {
        uint4 a = p[2 * i], bq = p[2 * i + 1];
        c[i] = a.x + a.y + a.z + a.w + bq.x + bq.y + bq.z + bq.w;
    }
    unsigned s0 = c[0], s1 = s0 + c[1], s2 = s1 + c[2], ts = s2 + c[3];
    unsigned sc = ts;
#pragma unroll
    for (int d = 1; d < 64; d <<= 1) {
        unsigned o = __shfl_up(sc, d);
        if (lane >= d) sc += o;
    }
    if (lane == 63) wtot[wid] = sc;
    __syncthreads();
    unsigned wpre = 0;
#pragma unroll
    for (int k = 0; k < 4; ++k) wpre += (k < wid) ? wtot[k] : 0u;
    unsigned excl = wpre + sc - ts;
    ((uint4*)base)[t] = make_uint4(excl, excl + s0, excl + s1, excl + s2);
    if (t == 255) base[1024] = wpre + sc;
}

// ---------------------------------------------------------------------------
// K3: ordered compaction (blocks 0..1023) + -1 tail fill (blocks 1024..),
// int4-vectorized tail body.
// ---------------------------------------------------------------------------
__global__ __launch_bounds__(256) void nms_compact(const unsigned* __restrict__ words,
                                                   const unsigned* __restrict__ base,
                                                   int* __restrict__ out) {
    const int t = threadIdx.x;
    const int b = blockIdx.x;
    if (b < 1024) {
        __shared__ unsigned wq[4];
        const int lane = t & 63, wid = t >> 6;
        uint4 q = ((const uint4*)(words + b * 1024))[t];
        unsigned wv[4] = {q.x, q.y, q.z, q.w};
        unsigned tsum = __popc(wv[0]) + __popc(wv[1]) + __popc(wv[2]) + __popc(wv[3]);
        unsigned sc = tsum;
#pragma unroll
        for (int d = 1; d < 64; d <<= 1) {
            unsigned o = __shfl_up(sc, d);
            if (lane >= d) sc += o;
        }
        if (lane == 63) wq[wid] = sc;
        __syncthreads();
        unsigned wpre = 0;
#pragma unroll
        for (int k = 0; k < 4; ++k) wpre += (k < wid) ? wq[k] : 0u;
        unsigned off = base[b] + wpre + sc - tsum;

        const unsigned gword0 = (unsigned)b * 1024u + (unsigned)t * 4u;
#pragma unroll
        for (int wi = 0; wi < 4; ++wi) {
            unsigned m = wv[wi];
            unsigned pbase = (gword0 + wi) << 5;
            while (m) {
                int bit = __builtin_ctz(m);
                m &= m - 1;
                unsigned ppix = pbase + (unsigned)bit;
                int hh = (int)((ppix >> 11) & 2047u);
                int ww = (int)(ppix & 2047u);
                if (off < (unsigned)MAX_PEAKS) {
                    out[off] = hh;
                    out[MAX_PEAKS + off] = ww;
                }
                ++off;
            }
        }
    } else {
        unsigned total = base[1024];
        if (total > (unsigned)MAX_PEAKS) total = MAX_PEAKS;
        unsigned tail = (unsigned)MAX_PEAKS - total;
        unsigned fb = (unsigned)(b - 1024);
        unsigned per = (tail + NFILL - 1) / NFILL;
        unsigned s = total + fb * per;
        unsigned e = s + per;
        if (s > (unsigned)MAX_PEAKS) s = MAX_PEAKS;
        if (e > (unsigned)MAX_PEAKS) e = MAX_PEAKS;
        unsigned a = (s + 3u) & ~3u;
        if (a > e) a = e;
        unsigned e4 = e & ~3u;
        if (e4 < a) e4 = a;
        if ((unsigned)t < a - s) {
            out[s + t] = -1;
            out[MAX_PEAKS + s + t] = -1;
        }
        const int4 m4 = make_int4(-1, -1, -1, -1);
        for (unsigned k = a / 4 + t; k < e4 / 4; k += 256) {
            ((int4*)out)[k] = m4;
            ((int4*)(out + MAX_PEAKS))[k] = m4;
        }
        if ((unsigned)t < e - e4) {
            out[e4 + t] = -1;
            out[MAX_PEAKS + e4 + t] = -1;
        }
    }
}

extern "C" void kernel_launch(void* const* d_in, const int* in_sizes, int n_in,
                              void* d_out, int out_size, void* d_ws, size_t ws_size,
                              hipStream_t stream) {
    const float* scores = (const float*)d_in[0];
    int* out = (int*)d_out;
    unsigned* words = (unsigned*)d_ws;            // 1,048,576 words (4 MB)
    unsigned* bsum2 = words + NWORDS;             // 8192 per-(16-row,strip) sums
    unsigned* base = bsum2 + 8192;                // 1025 (incl. total)

    nms_mask<<<2048, 256, 0, stream>>>(scores, words, bsum2);
    nms_scan<<<1, 256, 0, stream>>>(bsum2, base);
    nms_compact<<<1024 + NFILL, 256, 0, stream>>>(words, base, out);
}